// Round 3
// baseline (1026.076 us; speedup 1.0000x reference)
//
#include <hip/hip_runtime.h>
#include <hip/hip_bf16.h>
#include <stdint.h>

#define DMODEL 1024
#define NEXP   8
#define HSZ    4096
#define NTOK   4096   // B*S
#define SK     4      // split-K factor for GEMM2

typedef __attribute__((ext_vector_type(8))) short bf16x8;
typedef __attribute__((ext_vector_type(4))) float f32x4;

// fp32 -> bf16 round-to-nearest
__device__ __forceinline__ unsigned short f2bf(float f) {
  union { float f; unsigned u; } v; v.f = f;
  return (unsigned short)((v.u + 0x8000u) >> 16);
}

// async 16B/lane global->LDS DMA. Global addr per-lane; LDS dest wave-uniform,
// HW scatters lane l -> lds + l*16.
__device__ __forceinline__ void gl2lds16(const void* g, void* lds) {
  __builtin_amdgcn_global_load_lds(
      (const __attribute__((address_space(1))) unsigned*)g,
      (__attribute__((address_space(3))) unsigned*)lds, 16, 0, 0);
}

// ---------------- fused fp32 -> bf16 bulk convert (x, w1, w2) --------------
__global__ __launch_bounds__(256) void cvt_all_kernel(
    const float* __restrict__ x, const float* __restrict__ w1,
    const float* __restrict__ w2, unsigned short* __restrict__ xb,
    unsigned short* __restrict__ w1b, unsigned short* __restrict__ w2b) {
  const size_t n0 = (size_t)NTOK * DMODEL / 4;
  const size_t n1 = (size_t)NEXP * HSZ * DMODEL / 4;
  size_t i = (size_t)blockIdx.x * 256 + threadIdx.x;
  const float* src; unsigned short* dst; size_t j;
  if (i < n0)            { src = x;  dst = xb;  j = i; }
  else if (i < n0 + n1)  { src = w1; dst = w1b; j = i - n0; }
  else                   { src = w2; dst = w2b; j = i - n0 - n1; }
  float4 v = ((const float4*)src)[j];
  ((ushort4*)dst)[j] = make_ushort4(f2bf(v.x), f2bf(v.y), f2bf(v.z), f2bf(v.w));
}

// ---------------- router: 4 waves/block, 1 token/wave ----------------------
__global__ __launch_bounds__(256) void router_kernel(
    const float* __restrict__ x, const float* __restrict__ gw,
    int* __restrict__ cnt, int* __restrict__ tokl, float* __restrict__ twgt) {
  int wave = threadIdx.x >> 6;
  int lane = threadIdx.x & 63;
  int t = blockIdx.x * 4 + wave;
  const float* xr = x + (size_t)t * DMODEL;
  float acc[NEXP];
#pragma unroll
  for (int e = 0; e < NEXP; ++e) acc[e] = 0.f;
  for (int d = lane; d < DMODEL; d += 64) {
    float xv = xr[d];
#pragma unroll
    for (int e = 0; e < NEXP; ++e) acc[e] = fmaf(xv, gw[e * DMODEL + d], acc[e]);
  }
#pragma unroll
  for (int e = 0; e < NEXP; ++e) {
#pragma unroll
    for (int o = 32; o > 0; o >>= 1) acc[e] += __shfl_down(acc[e], o);
  }
  if (lane == 0) {
    float m = acc[0];
#pragma unroll
    for (int e = 1; e < NEXP; ++e) m = fmaxf(m, acc[e]);
    float p[NEXP]; float s = 0.f;
#pragma unroll
    for (int e = 0; e < NEXP; ++e) { p[e] = __expf(acc[e] - m); s += p[e]; }
    float inv = 1.f / s;
    int i0 = 0; float b0 = p[0];
#pragma unroll
    for (int e = 1; e < NEXP; ++e) if (p[e] > b0) { b0 = p[e]; i0 = e; }
    int i1 = (i0 == 0) ? 1 : 0; float b1v = p[i1];
#pragma unroll
    for (int e = 0; e < NEXP; ++e) if (e != i0 && p[e] > b1v) { b1v = p[e]; i1 = e; }
    int p0 = atomicAdd(&cnt[i0], 1);
    tokl[i0 * NTOK + p0] = t; twgt[i0 * NTOK + p0] = b0 * inv;
    int p1 = atomicAdd(&cnt[i1], 1);
    tokl[i1 * NTOK + p1] = t; twgt[i1 * NTOK + p1] = b1v * inv;
  }
}

// ---------------- GEMM1: H = relu(Xg @ w1^T + b1), bf16 out ----------------
// grid (HSZ/128, NTOK/128, NEXP), block 256
__global__ __launch_bounds__(256) void gemm1_bf_kernel(
    const unsigned short* __restrict__ Xbf, const unsigned short* __restrict__ W1bf,
    const float* __restrict__ b1, const int* __restrict__ cnt,
    const int* __restrict__ tokl, unsigned short* __restrict__ Hbuf) {
  const int e = blockIdx.z;
  const int ne = cnt[e];
  const int m0 = blockIdx.y * 128;
  if (m0 >= ne) return;
  const int n0 = blockIdx.x * 128;
  // inline exclusive prefix over 8 counts (cnt final: router ran before us)
  int toff = 0;
  for (int i = 0; i < NEXP; ++i) toff += (i < e) ? cnt[i] : 0;

  __shared__ __align__(16) unsigned short As[128 * 32];
  __shared__ __align__(16) unsigned short Bs[128 * 32];

  const int tid = threadIdx.x;
  const int lane = tid & 63;
  const int wave = tid >> 6;
  const int wm = (wave >> 1) * 64;
  const int wn = (wave & 1) * 64;

  const int srow = wave * 16 + (lane >> 2);
  const int scol = (lane & 3) * 8;
  const int* tlist = tokl + e * NTOK;
  const unsigned short* gA[2]; const unsigned short* gB[2];
  unsigned short* lA[2]; unsigned short* lB[2];
#pragma unroll
  for (int c = 0; c < 2; ++c) {
    int r = c * 64 + srow;
    int gr = m0 + r;
    int tk = tlist[(gr < ne) ? gr : 0];
    gA[c] = Xbf + (size_t)tk * DMODEL + scol;
    gB[c] = W1bf + (size_t)e * HSZ * DMODEL + (size_t)(n0 + r) * DMODEL + scol;
    lA[c] = &As[(c * 64 + wave * 16) * 32];
    lB[c] = &Bs[(c * 64 + wave * 16) * 32];
  }

  f32x4 acc[4][4];
#pragma unroll
  for (int i = 0; i < 4; ++i)
#pragma unroll
    for (int j = 0; j < 4; ++j) acc[i][j] = (f32x4){0.f, 0.f, 0.f, 0.f};

  const int fr = lane & 15;
  const int fk = (lane >> 4) * 8;

  for (int k0 = 0; k0 < DMODEL; k0 += 32) {
    __syncthreads();
#pragma unroll
    for (int c = 0; c < 2; ++c) {
      gl2lds16(gA[c] + k0, lA[c]);
      gl2lds16(gB[c] + k0, lB[c]);
    }
    __syncthreads();
    bf16x8 af[4], bfg[4];
#pragma unroll
    for (int i = 0; i < 4; ++i) {
      af[i]  = *(const bf16x8*)&As[(wm + i * 16 + fr) * 32 + fk];
      bfg[i] = *(const bf16x8*)&Bs[(wn + i * 16 + fr) * 32 + fk];
    }
    // operand swap: D[m=hidden][n=token]; lane's 4 regs = 4 contiguous hidden cols
#pragma unroll
    for (int i = 0; i < 4; ++i)
#pragma unroll
      for (int j = 0; j < 4; ++j)
        acc[i][j] = __builtin_amdgcn_mfma_f32_16x16x32_bf16(bfg[j], af[i], acc[i][j], 0, 0, 0);
  }

  const int hq = (lane >> 4) * 4;
#pragma unroll
  for (int i = 0; i < 4; ++i) {
    int trow = m0 + wm + i * 16 + fr;
    if (trow >= ne) continue;
    size_t hrow = (size_t)(toff + trow) * HSZ;
#pragma unroll
    for (int j = 0; j < 4; ++j) {
      int hcol = n0 + wn + j * 16 + hq;
      const float* bp = b1 + e * HSZ + hcol;
      unsigned short u[4];
#pragma unroll
      for (int r = 0; r < 4; ++r)
        u[r] = f2bf(fmaxf(acc[i][j][r] + bp[r], 0.f));
      *(ushort4*)&Hbuf[hrow + hcol] = make_ushort4(u[0], u[1], u[2], u[3]);
    }
  }
}

// ---------------- GEMM2 split-K: out[tok] += w * (H @ w2^T + b2) -----------
// grid (8*SK, NTOK/128, NEXP): bx = kz*8 + n-block
__global__ __launch_bounds__(256) void gemm2_bf_kernel(
    const unsigned short* __restrict__ Hbuf, const unsigned short* __restrict__ W2bf,
    const float* __restrict__ b2, const int* __restrict__ cnt,
    const int* __restrict__ tokl, const float* __restrict__ twgt,
    float* __restrict__ out) {
  const int e = blockIdx.z;
  const int ne = cnt[e];
  const int m0 = blockIdx.y * 128;
  if (m0 >= ne) return;
  const int n0 = (blockIdx.x & 7) * 128;
  const int kz = blockIdx.x >> 3;
  const int kbase = kz * (HSZ / SK);
  int toff = 0;
  for (int i = 0; i < NEXP; ++i) toff += (i < e) ? cnt[i] : 0;

  __shared__ __align__(16) unsigned short As[128 * 32];
  __shared__ __align__(16) unsigned short Bs[128 * 32];

  const int tid = threadIdx.x;
  const int lane = tid & 63;
  const int wave = tid >> 6;
  const int wm = (wave >> 1) * 64;
  const int wn = (wave & 1) * 64;

  const int srow = wave * 16 + (lane >> 2);
  const int scol = (lane & 3) * 8;
  const unsigned short* gA[2]; const unsigned short* gB[2];
  unsigned short* lA[2]; unsigned short* lB[2];
#pragma unroll
  for (int c = 0; c < 2; ++c) {
    int r = c * 64 + srow;
    int gr = m0 + r;
    int rc = (gr < ne) ? gr : 0;
    gA[c] = Hbuf + (size_t)(toff + rc) * HSZ + scol;
    gB[c] = W2bf + (size_t)e * DMODEL * HSZ + (size_t)(n0 + r) * HSZ + scol;
    lA[c] = &As[(c * 64 + wave * 16) * 32];
    lB[c] = &Bs[(c * 64 + wave * 16) * 32];
  }

  f32x4 acc[4][4];
#pragma unroll
  for (int i = 0; i < 4; ++i)
#pragma unroll
    for (int j = 0; j < 4; ++j) acc[i][j] = (f32x4){0.f, 0.f, 0.f, 0.f};

  const int fr = lane & 15;
  const int fk = (lane >> 4) * 8;

  for (int k0 = kbase; k0 < kbase + HSZ / SK; k0 += 32) {
    __syncthreads();
#pragma unroll
    for (int c = 0; c < 2; ++c) {
      gl2lds16(gA[c] + k0, lA[c]);
      gl2lds16(gB[c] + k0, lB[c]);
    }
    __syncthreads();
    bf16x8 af[4], bfg[4];
#pragma unroll
    for (int i = 0; i < 4; ++i) {
      af[i]  = *(const bf16x8*)&As[(wm + i * 16 + fr) * 32 + fk];
      bfg[i] = *(const bf16x8*)&Bs[(wn + i * 16 + fr) * 32 + fk];
    }
#pragma unroll
    for (int i = 0; i < 4; ++i)
#pragma unroll
      for (int j = 0; j < 4; ++j)
        acc[i][j] = __builtin_amdgcn_mfma_f32_16x16x32_bf16(bfg[j], af[i], acc[i][j], 0, 0, 0);
  }

  const int* tlist = tokl + e * NTOK;
  const float* wlist = twgt + e * NTOK;
  const int dq = (lane >> 4) * 4;
#pragma unroll
  for (int i = 0; i < 4; ++i) {
    int trow = m0 + wm + i * 16 + fr;
    if (trow >= ne) continue;
    int tkn = tlist[trow];
    float wgt = wlist[trow];
    float* orow = out + (size_t)tkn * DMODEL;
#pragma unroll
    for (int j = 0; j < 4; ++j) {
      int d0 = n0 + wn + j * 16 + dq;
      const float* b2p = b2 + e * DMODEL + d0;
#pragma unroll
      for (int r = 0; r < 4; ++r) {
        float v = acc[i][j][r] + ((kz == 0) ? b2p[r] : 0.f);  // bias once
        atomicAdd(orow + d0 + r, wgt * v);
      }
    }
  }
}

extern "C" void kernel_launch(void* const* d_in, const int* in_sizes, int n_in,
                              void* d_out, int out_size, void* d_ws, size_t ws_size,
                              hipStream_t stream) {
  const float* x  = (const float*)d_in[0];
  const float* gw = (const float*)d_in[1];
  const float* w1 = (const float*)d_in[2];
  const float* b1 = (const float*)d_in[3];
  const float* w2 = (const float*)d_in[4];
  const float* b2 = (const float*)d_in[5];
  float* out = (float*)d_out;

  char* ws = (char*)d_ws;
  int* cnt    = (int*)ws;                                  // 8 ints
  int* tokl   = (int*)(ws + 128);                          // 8*4096 ints = 128 KB
  float* twgt = (float*)(ws + 128 + NEXP * NTOK * 4);      // 128 KB

  constexpr size_t OFF_XBF  = 262144;
  constexpr size_t OFF_W1BF = OFF_XBF  + (size_t)NTOK * DMODEL * 2;
  constexpr size_t OFF_W2BF = OFF_W1BF + (size_t)NEXP * HSZ * DMODEL * 2;
  constexpr size_t OFF_HBUF = OFF_W2BF + (size_t)NEXP * DMODEL * HSZ * 2;
  unsigned short* Xbf  = (unsigned short*)(ws + OFF_XBF);
  unsigned short* W1bf = (unsigned short*)(ws + OFF_W1BF);
  unsigned short* W2bf = (unsigned short*)(ws + OFF_W2BF);
  unsigned short* Hbuf = (unsigned short*)(ws + OFF_HBUF);

  hipMemsetAsync(cnt, 0, 32, stream);
  hipMemsetAsync(out, 0, (size_t)NTOK * DMODEL * sizeof(float), stream);
  router_kernel<<<NTOK / 4, 256, 0, stream>>>(x, gw, cnt, tokl, twgt);
  const size_t ncvt = (size_t)NTOK * DMODEL / 4 + 2 * (size_t)NEXP * HSZ * DMODEL / 4;
  cvt_all_kernel<<<(unsigned)((ncvt + 255) / 256), 256, 0, stream>>>(
      x, w1, w2, Xbf, W1bf, W2bf);
  gemm1_bf_kernel<<<dim3(HSZ / 128, NTOK / 128, NEXP), 256, 0, stream>>>(
      Xbf, W1bf, b1, cnt, tokl, Hbuf);
  gemm2_bf_kernel<<<dim3(8 * SK, NTOK / 128, NEXP), 256, 0, stream>>>(
      Hbuf, W2bf, b2, cnt, tokl, twgt, out);
}

// Round 4
// 665.811 us; speedup vs baseline: 1.5411x; 1.5411x over previous
//
#include <hip/hip_runtime.h>
#include <hip/hip_bf16.h>
#include <stdint.h>

#define DMODEL 1024
#define NEXP   8
#define HSZ    4096
#define NTOK   4096   // B*S

typedef __attribute__((ext_vector_type(8))) short bf16x8;
typedef __attribute__((ext_vector_type(4))) float f32x4;

// fp32 -> bf16 round-to-nearest
__device__ __forceinline__ unsigned short f2bf(float f) {
  union { float f; unsigned u; } v; v.f = f;
  return (unsigned short)((v.u + 0x8000u) >> 16);
}

// async 16B/lane global->LDS DMA. Per-lane global addr; LDS dest wave-uniform,
// HW scatters lane l -> lds + l*16.
__device__ __forceinline__ void gl2lds16(const void* g, void* lds) {
  __builtin_amdgcn_global_load_lds(
      (const __attribute__((address_space(1))) unsigned*)g,
      (__attribute__((address_space(3))) unsigned*)lds, 16, 0, 0);
}

// ---------------- fused fp32 -> bf16 bulk convert (x, w1, w2) --------------
__global__ __launch_bounds__(256) void cvt_all_kernel(
    const float* __restrict__ x, const float* __restrict__ w1,
    const float* __restrict__ w2, unsigned short* __restrict__ xb,
    unsigned short* __restrict__ w1b, unsigned short* __restrict__ w2b) {
  const size_t n0 = (size_t)NTOK * DMODEL / 4;
  const size_t n1 = (size_t)NEXP * HSZ * DMODEL / 4;
  size_t i = (size_t)blockIdx.x * 256 + threadIdx.x;
  const float* src; unsigned short* dst; size_t j;
  if (i < n0)            { src = x;  dst = xb;  j = i; }
  else if (i < n0 + n1)  { src = w1; dst = w1b; j = i - n0; }
  else                   { src = w2; dst = w2b; j = i - n0 - n1; }
  float4 v = ((const float4*)src)[j];
  ((ushort4*)dst)[j] = make_ushort4(f2bf(v.x), f2bf(v.y), f2bf(v.z), f2bf(v.w));
}

// ---------------- router: 4 waves/block, 1 token/wave ----------------------
// Also records per-token (expert,slot) so combine can find its 2 Y rows.
__global__ __launch_bounds__(256) void router_kernel(
    const float* __restrict__ x, const float* __restrict__ gw,
    int* __restrict__ cnt, int* __restrict__ tokl, float* __restrict__ twgt,
    int* __restrict__ sidx) {
  int wave = threadIdx.x >> 6;
  int lane = threadIdx.x & 63;
  int t = blockIdx.x * 4 + wave;
  const float* xr = x + (size_t)t * DMODEL;
  float acc[NEXP];
#pragma unroll
  for (int e = 0; e < NEXP; ++e) acc[e] = 0.f;
  for (int d = lane; d < DMODEL; d += 64) {
    float xv = xr[d];
#pragma unroll
    for (int e = 0; e < NEXP; ++e) acc[e] = fmaf(xv, gw[e * DMODEL + d], acc[e]);
  }
#pragma unroll
  for (int e = 0; e < NEXP; ++e) {
#pragma unroll
    for (int o = 32; o > 0; o >>= 1) acc[e] += __shfl_down(acc[e], o);
  }
  if (lane == 0) {
    float m = acc[0];
#pragma unroll
    for (int e = 1; e < NEXP; ++e) m = fmaxf(m, acc[e]);
    float p[NEXP]; float s = 0.f;
#pragma unroll
    for (int e = 0; e < NEXP; ++e) { p[e] = __expf(acc[e] - m); s += p[e]; }
    float inv = 1.f / s;
    int i0 = 0; float b0 = p[0];
#pragma unroll
    for (int e = 1; e < NEXP; ++e) if (p[e] > b0) { b0 = p[e]; i0 = e; }
    int i1 = (i0 == 0) ? 1 : 0; float b1v = p[i1];
#pragma unroll
    for (int e = 0; e < NEXP; ++e) if (e != i0 && p[e] > b1v) { b1v = p[e]; i1 = e; }
    int p0 = atomicAdd(&cnt[i0], 1);
    tokl[i0 * NTOK + p0] = t; twgt[i0 * NTOK + p0] = b0 * inv;
    int p1 = atomicAdd(&cnt[i1], 1);
    tokl[i1 * NTOK + p1] = t; twgt[i1 * NTOK + p1] = b1v * inv;
    sidx[2 * t]     = (i0 << 16) | p0;
    sidx[2 * t + 1] = (i1 << 16) | p1;
  }
}

// ---------------- GEMM1: H = relu(Xg @ w1^T + b1), bf16 out ----------------
// grid (HSZ/128, NTOK/128, NEXP), block 256, BK=32 (unchanged from R2)
__global__ __launch_bounds__(256) void gemm1_bf_kernel(
    const unsigned short* __restrict__ Xbf, const unsigned short* __restrict__ W1bf,
    const float* __restrict__ b1, const int* __restrict__ cnt,
    const int* __restrict__ tokl, unsigned short* __restrict__ Hbuf) {
  const int e = blockIdx.z;
  const int ne = cnt[e];
  const int m0 = blockIdx.y * 128;
  if (m0 >= ne) return;
  const int n0 = blockIdx.x * 128;
  int toff = 0;
  for (int i = 0; i < NEXP; ++i) toff += (i < e) ? cnt[i] : 0;

  __shared__ __align__(16) unsigned short As[128 * 32];
  __shared__ __align__(16) unsigned short Bs[128 * 32];

  const int tid = threadIdx.x;
  const int lane = tid & 63;
  const int wave = tid >> 6;
  const int wm = (wave >> 1) * 64;
  const int wn = (wave & 1) * 64;

  const int srow = wave * 16 + (lane >> 2);
  const int scol = (lane & 3) * 8;
  const int* tlist = tokl + e * NTOK;
  const unsigned short* gA[2]; const unsigned short* gB[2];
  unsigned short* lA[2]; unsigned short* lB[2];
#pragma unroll
  for (int c = 0; c < 2; ++c) {
    int r = c * 64 + srow;
    int gr = m0 + r;
    int tk = tlist[(gr < ne) ? gr : 0];
    gA[c] = Xbf + (size_t)tk * DMODEL + scol;
    gB[c] = W1bf + (size_t)e * HSZ * DMODEL + (size_t)(n0 + r) * DMODEL + scol;
    lA[c] = &As[(c * 64 + wave * 16) * 32];
    lB[c] = &Bs[(c * 64 + wave * 16) * 32];
  }

  f32x4 acc[4][4];
#pragma unroll
  for (int i = 0; i < 4; ++i)
#pragma unroll
    for (int j = 0; j < 4; ++j) acc[i][j] = (f32x4){0.f, 0.f, 0.f, 0.f};

  const int fr = lane & 15;
  const int fk = (lane >> 4) * 8;

  for (int k0 = 0; k0 < DMODEL; k0 += 32) {
    __syncthreads();
#pragma unroll
    for (int c = 0; c < 2; ++c) {
      gl2lds16(gA[c] + k0, lA[c]);
      gl2lds16(gB[c] + k0, lB[c]);
    }
    __syncthreads();
    bf16x8 af[4], bfg[4];
#pragma unroll
    for (int i = 0; i < 4; ++i) {
      af[i]  = *(const bf16x8*)&As[(wm + i * 16 + fr) * 32 + fk];
      bfg[i] = *(const bf16x8*)&Bs[(wn + i * 16 + fr) * 32 + fk];
    }
    // operand swap: D[m=hidden][n=token]; lane's 4 regs = 4 contiguous hidden cols
#pragma unroll
    for (int i = 0; i < 4; ++i)
#pragma unroll
      for (int j = 0; j < 4; ++j)
        acc[i][j] = __builtin_amdgcn_mfma_f32_16x16x32_bf16(bfg[j], af[i], acc[i][j], 0, 0, 0);
  }

  const int hq = (lane >> 4) * 4;
#pragma unroll
  for (int i = 0; i < 4; ++i) {
    int trow = m0 + wm + i * 16 + fr;
    if (trow >= ne) continue;
    size_t hrow = (size_t)(toff + trow) * HSZ;
#pragma unroll
    for (int j = 0; j < 4; ++j) {
      int hcol = n0 + wn + j * 16 + hq;
      const float* bp = b1 + e * HSZ + hcol;
      unsigned short u[4];
#pragma unroll
      for (int r = 0; r < 4; ++r)
        u[r] = f2bf(fmaxf(acc[i][j][r] + bp[r], 0.f));
      *(ushort4*)&Hbuf[hrow + hcol] = make_ushort4(u[0], u[1], u[2], u[3]);
    }
  }
}

// ---------------- GEMM2: Y[row] = w * (H @ w2^T + b2), plain stores --------
// grid (DMODEL/128, NTOK/128, NEXP), block 256, BK=64 + XOR-swizzled LDS
__global__ __launch_bounds__(256) void gemm2_bf_kernel(
    const unsigned short* __restrict__ Hbuf, const unsigned short* __restrict__ W2bf,
    const float* __restrict__ b2, const int* __restrict__ cnt,
    const float* __restrict__ twgt, float* __restrict__ Ybuf) {
  const int e = blockIdx.z;
  const int ne = cnt[e];
  const int m0 = blockIdx.y * 128;
  if (m0 >= ne) return;
  const int n0 = blockIdx.x * 128;
  int toff = 0;
  for (int i = 0; i < NEXP; ++i) toff += (i < e) ? cnt[i] : 0;

  __shared__ __align__(16) unsigned short As[128 * 64];  // 16 KB, swizzled
  __shared__ __align__(16) unsigned short Bs[128 * 64];

  const int tid = threadIdx.x;
  const int lane = tid & 63;
  const int wave = tid >> 6;
  const int wm = (wave >> 1) * 64;
  const int wn = (wave & 1) * 64;

  // DMA staging: call c covers rows wave*32 + c*8 + (lane>>3); lane's 16B slot
  // (lane&7) holds global col-block (lane&7)^(lane>>3) -> XOR swizzle. Global
  // reads stay coalesced (8 lanes permute within one 128B row segment).
  const int srow = (wave << 5) + (lane >> 3);
  const int scb  = (((lane & 7) ^ (lane >> 3)) << 3);  // elem offset 0..56
  const unsigned short* gA[4]; const unsigned short* gB[4];
  unsigned short* lA[4]; unsigned short* lB[4];
#pragma unroll
  for (int c = 0; c < 4; ++c) {
    int r = srow + c * 8;          // 0..127
    int gr = m0 + r;
    int rc = (gr < ne) ? gr : 0;
    gA[c] = Hbuf + (size_t)(toff + rc) * HSZ + scb;
    gB[c] = W2bf + (size_t)e * DMODEL * HSZ + (size_t)(n0 + r) * HSZ + scb;
    lA[c] = &As[((wave << 5) + c * 8) * 64];
    lB[c] = &Bs[((wave << 5) + c * 8) * 64];
  }

  f32x4 acc[4][4];
#pragma unroll
  for (int i = 0; i < 4; ++i)
#pragma unroll
    for (int j = 0; j < 4; ++j) acc[i][j] = (f32x4){0.f, 0.f, 0.f, 0.f};

  const int fr = lane & 15;
  const int cb0 = lane >> 4;  // 0..3

  for (int k0 = 0; k0 < HSZ; k0 += 64) {
    __syncthreads();
#pragma unroll
    for (int c = 0; c < 4; ++c) {
      gl2lds16(gA[c] + k0, lA[c]);
      gl2lds16(gB[c] + k0, lB[c]);
    }
    __syncthreads();
    bf16x8 af[2][4], bfg[2][4];
#pragma unroll
    for (int h = 0; h < 2; ++h) {
      int cb = cb0 + h * 4;
#pragma unroll
      for (int i = 0; i < 4; ++i) {
        int ar = wm + i * 16 + fr;
        af[h][i]  = *(const bf16x8*)&As[ar * 64 + ((cb ^ (ar & 7)) << 3)];
        int br = wn + i * 16 + fr;
        bfg[h][i] = *(const bf16x8*)&Bs[br * 64 + ((cb ^ (br & 7)) << 3)];
      }
    }
#pragma unroll
    for (int h = 0; h < 2; ++h)
#pragma unroll
      for (int i = 0; i < 4; ++i)
#pragma unroll
        for (int j = 0; j < 4; ++j)
          acc[i][j] = __builtin_amdgcn_mfma_f32_16x16x32_bf16(bfg[h][j], af[h][i],
                                                              acc[i][j], 0, 0, 0);
  }

  const float* wlist = twgt + e * NTOK;
  const int dq = (lane >> 4) * 4;
#pragma unroll
  for (int i = 0; i < 4; ++i) {
    int trow = m0 + wm + i * 16 + fr;
    if (trow >= ne) continue;
    float wgt = wlist[trow];
    float* yrow = Ybuf + (size_t)(toff + trow) * DMODEL;
#pragma unroll
    for (int j = 0; j < 4; ++j) {
      int d0 = n0 + wn + j * 16 + dq;
      const float* b2p = b2 + e * DMODEL + d0;
      float4 v = make_float4(wgt * (acc[i][j][0] + b2p[0]),
                             wgt * (acc[i][j][1] + b2p[1]),
                             wgt * (acc[i][j][2] + b2p[2]),
                             wgt * (acc[i][j][3] + b2p[3]));
      *(float4*)(yrow + d0) = v;
    }
  }
}

// ---------------- combine: out[t] = Y[r0(t)] + Y[r1(t)] --------------------
// grid NTOK, block 256 (one token/block, thread i -> cols 4i..4i+3)
__global__ __launch_bounds__(256) void combine_kernel(
    const float* __restrict__ Ybuf, const int* __restrict__ cnt,
    const int* __restrict__ sidx, float* __restrict__ out) {
  int t = blockIdx.x;
  int offv[NEXP];
  int s = 0;
#pragma unroll
  for (int e = 0; e < NEXP; ++e) { offv[e] = s; s += cnt[e]; }
  int s0 = sidx[2 * t], s1 = sidx[2 * t + 1];
  size_t r0 = (size_t)(offv[s0 >> 16] + (s0 & 0xffff)) * DMODEL;
  size_t r1 = (size_t)(offv[s1 >> 16] + (s1 & 0xffff)) * DMODEL;
  int c = threadIdx.x * 4;
  float4 a = *(const float4*)(Ybuf + r0 + c);
  float4 b = *(const float4*)(Ybuf + r1 + c);
  *(float4*)(out + (size_t)t * DMODEL + c) =
      make_float4(a.x + b.x, a.y + b.y, a.z + b.z, a.w + b.w);
}

extern "C" void kernel_launch(void* const* d_in, const int* in_sizes, int n_in,
                              void* d_out, int out_size, void* d_ws, size_t ws_size,
                              hipStream_t stream) {
  const float* x  = (const float*)d_in[0];
  const float* gw = (const float*)d_in[1];
  const float* w1 = (const float*)d_in[2];
  const float* b1 = (const float*)d_in[3];
  const float* w2 = (const float*)d_in[4];
  const float* b2 = (const float*)d_in[5];
  float* out = (float*)d_out;

  char* ws = (char*)d_ws;
  int* cnt    = (int*)ws;                                  // 32 B
  int* tokl   = (int*)(ws + 128);                          // 128 KB
  float* twgt = (float*)(ws + 128 + NEXP * NTOK * 4);      // 128 KB
  int* sidx   = (int*)(ws + 128 + 2 * NEXP * NTOK * 4);    // 32 KB

  constexpr size_t OFF_XBF  = 327680;                                      // 320 KB
  constexpr size_t OFF_W1BF = OFF_XBF  + (size_t)NTOK * DMODEL * 2;        // +8 MB
  constexpr size_t OFF_W2BF = OFF_W1BF + (size_t)NEXP * HSZ * DMODEL * 2;  // +64 MB
  constexpr size_t OFF_HBUF = OFF_W2BF + (size_t)NEXP * DMODEL * HSZ * 2;  // +64 MB
  unsigned short* Xbf  = (unsigned short*)(ws + OFF_XBF);
  unsigned short* W1bf = (unsigned short*)(ws + OFF_W1BF);
  unsigned short* W2bf = (unsigned short*)(ws + OFF_W2BF);
  unsigned short* Hbuf = (unsigned short*)(ws + OFF_HBUF);
  // Ybuf overlays W1bf (dead after gemm1; stream order guarantees safety)
  float* Ybuf = (float*)(ws + OFF_W1BF);

  hipMemsetAsync(cnt, 0, 32, stream);
  router_kernel<<<NTOK / 4, 256, 0, stream>>>(x, gw, cnt, tokl, twgt, sidx);
  const size_t ncvt = (size_t)NTOK * DMODEL / 4 + 2 * (size_t)NEXP * HSZ * DMODEL / 4;
  cvt_all_kernel<<<(unsigned)((ncvt + 255) / 256), 256, 0, stream>>>(
      x, w1, w2, Xbf, W1bf, W2bf);
  gemm1_bf_kernel<<<dim3(HSZ / 128, NTOK / 128, NEXP), 256, 0, stream>>>(
      Xbf, W1bf, b1, cnt, tokl, Hbuf);
  gemm2_bf_kernel<<<dim3(DMODEL / 128, NTOK / 128, NEXP), 256, 0, stream>>>(
      Hbuf, W2bf, b2, cnt, twgt, Ybuf);
  combine_kernel<<<NTOK, 256, 0, stream>>>(Ybuf, cnt, sidx, out);
}